// Round 2
// baseline (501.763 us; speedup 1.0000x reference)
//
#include <hip/hip_runtime.h>

// OU scan: x_s = c_s * x_{s-1} + sqrt(1-c_s^2) * z_s,  c_s = exp(-theta*dt_s)
// B=64, S=4096, D=256. float32 in/out (per reference), f32 math.
// 3-pass chunked scan: per-chunk aggregates -> chunk-carry scan -> apply.

#define THETA 0.5f
constexpr int Bn = 64;
constexpr int Sn = 4096;
constexpr int Dn = 256;
constexpr int CHUNK = 64;           // rows per chunk
constexpr int NC = Sn / CHUNK;      // 64 chunks per batch

// ---------------- K1: per-chunk aggregates ----------------
// One wave (64 threads) per (b, chunk). Lane owns 4 consecutive d (float4).
// agg[b,k,d] = chunk-local scan result from zero state (chunk 0: x0 folded in).
__global__ __launch_bounds__(64) void k_agg(
    const float* __restrict__ t,    // [B,S]
    const float* __restrict__ x0,   // [B,D]
    const float* __restrict__ z,    // [B,S,D]
    float* __restrict__ agg)        // [B,NC,D]
{
    const int blk = blockIdx.x;
    const int b = blk / NC;
    const int k = blk % NC;
    const int lane = threadIdx.x;    // 0..63
    const int s0 = k * CHUNK;

    __shared__ float cs[CHUNK];
    __shared__ float ss[CHUNK];
    {
        const int r = s0 + lane;
        float tcur = t[b * Sn + r];
        float tprev = (r == 0) ? 0.0f : t[b * Sn + r - 1];
        float c = __expf(-THETA * (tcur - tprev));
        cs[lane] = c;
        ss[lane] = sqrtf(fmaxf(0.0f, 1.0f - c * c));
    }
    __syncthreads();

    const int d0 = lane * 4;
    float a0 = 0.f, a1 = 0.f, a2 = 0.f, a3 = 0.f;
    if (k == 0) {
        const float4 xv = *(const float4*)(x0 + (size_t)b * Dn + d0);
        a0 = xv.x; a1 = xv.y; a2 = xv.z; a3 = xv.w;
    }

    const float* zp = z + ((size_t)b * Sn + s0) * Dn + d0;
#pragma unroll 4
    for (int r = 0; r < CHUNK; ++r) {
        const float4 zv = *(const float4*)zp;
        zp += Dn;
        const float c = cs[r];
        const float sv = ss[r];
        a0 = fmaf(c, a0, sv * zv.x);
        a1 = fmaf(c, a1, sv * zv.y);
        a2 = fmaf(c, a2, sv * zv.z);
        a3 = fmaf(c, a3, sv * zv.w);
    }

    float4* ap = (float4*)(agg + ((size_t)b * NC + k) * Dn + d0);
    *ap = make_float4(a0, a1, a2, a3);
}

// ---------------- K2: scan chunk aggregates -> carry-in (in place) ----------
// One block per batch b; thread = d. A_k = exp(-theta*(t_end(k)-t_end(k-1))).
__global__ __launch_bounds__(256) void k_scan(
    const float* __restrict__ t,
    float* __restrict__ agg)        // in: aggregates, out: carry-in (exclusive)
{
    const int b = blockIdx.x;
    const int d = threadIdx.x;

    __shared__ float As[NC];
    if (d < NC) {
        const int k = d;
        float tend = t[b * Sn + k * CHUNK + CHUNK - 1];
        float tpe = (k == 0) ? 0.0f : t[b * Sn + k * CHUNK - 1];
        As[k] = __expf(-THETA * (tend - tpe));
    }
    __syncthreads();

    float cin = 0.0f;
    float* ap = agg + (size_t)b * NC * Dn + d;
#pragma unroll 8
    for (int k = 0; k < NC; ++k) {
        const float bk = ap[(size_t)k * Dn];
        ap[(size_t)k * Dn] = cin;            // exclusive: carry INTO chunk k
        cin = fmaf(As[k], cin, bk);
    }
}

// ---------------- K3: apply carries, write output ----------------
__global__ __launch_bounds__(64) void k_final(
    const float* __restrict__ t,
    const float* __restrict__ x0,
    const float* __restrict__ z,
    const float* __restrict__ carry,   // [B,NC,D]
    float* __restrict__ out)           // [B,S,D]
{
    const int blk = blockIdx.x;
    const int b = blk / NC;
    const int k = blk % NC;
    const int lane = threadIdx.x;
    const int s0 = k * CHUNK;

    __shared__ float cs[CHUNK];
    __shared__ float ss[CHUNK];
    {
        const int r = s0 + lane;
        float tcur = t[b * Sn + r];
        float tprev = (r == 0) ? 0.0f : t[b * Sn + r - 1];
        float c = __expf(-THETA * (tcur - tprev));
        cs[lane] = c;
        ss[lane] = sqrtf(fmaxf(0.0f, 1.0f - c * c));
    }
    __syncthreads();

    const int d0 = lane * 4;
    float a0, a1, a2, a3;
    if (k == 0) {
        const float4 xv = *(const float4*)(x0 + (size_t)b * Dn + d0);
        a0 = xv.x; a1 = xv.y; a2 = xv.z; a3 = xv.w;
    } else {
        const float4 cv = *(const float4*)(carry + ((size_t)b * NC + k) * Dn + d0);
        a0 = cv.x; a1 = cv.y; a2 = cv.z; a3 = cv.w;
    }

    const float* zp = z + ((size_t)b * Sn + s0) * Dn + d0;
    float* op = out + ((size_t)b * Sn + s0) * Dn + d0;
#pragma unroll 4
    for (int r = 0; r < CHUNK; ++r) {
        const float4 zv = *(const float4*)zp;
        zp += Dn;
        const float c = cs[r];
        const float sv = ss[r];
        a0 = fmaf(c, a0, sv * zv.x);
        a1 = fmaf(c, a1, sv * zv.y);
        a2 = fmaf(c, a2, sv * zv.z);
        a3 = fmaf(c, a3, sv * zv.w);
        *(float4*)op = make_float4(a0, a1, a2, a3);
        op += Dn;
    }
}

extern "C" void kernel_launch(void* const* d_in, const int* in_sizes, int n_in,
                              void* d_out, int out_size, void* d_ws, size_t ws_size,
                              hipStream_t stream) {
    const float* t  = (const float*)d_in[0];   // [B,S,1] f32
    const float* x0 = (const float*)d_in[1];   // [B,1,D] f32
    const float* z  = (const float*)d_in[2];   // [B,S,D] f32
    float* out = (float*)d_out;                // [B,S,D] f32

    float* agg = (float*)d_ws;   // [B,NC,D] = 4 MB: aggregates, then carry-ins

    k_agg<<<Bn * NC, 64, 0, stream>>>(t, x0, z, agg);
    k_scan<<<Bn, 256, 0, stream>>>(t, agg);
    k_final<<<Bn * NC, 64, 0, stream>>>(t, x0, z, agg, out);
}